// Round 1
// baseline (528.025 us; speedup 1.0000x reference)
//
#include <hip/hip_runtime.h>
#include <hip/hip_bf16.h>

// ---------------------------------------------------------------------------
// Problem constants
#define B_   4
#define SQ_  2048
#define SK_  2048
#define D_   1024
#define H_   16
#define HD_  64

typedef __bf16 bf16_t;
typedef bf16_t bf16x8 __attribute__((ext_vector_type(8)));
typedef bf16_t bf16x4 __attribute__((ext_vector_type(4)));
typedef float  f32x4  __attribute__((ext_vector_type(4)));

// MFMA 16x16x32 bf16 verified layouts (learn_hip m89/m91):
//   A operand: lane l, elem j -> A[m = l&15][k = (l>>4)*8 + j]
//   B operand: lane l, elem j -> B[k = (l>>4)*8 + j][n = l&15]
//   C/D:       lane l, reg  r -> D[m = (l>>4)*4 + r][n = l&15]

// ---------------------------------------------------------------------------
// QKV projection GEMM: out = X @ W^T + b, X fp32 [8192,1024], W fp32 [1024,1024]
// Output bf16 arranged [b][h][s][64] for attention.
// 128x128 tile, BK=32, 4 waves (2x2 of 64x64), fp32->bf16 convert in staging.
__global__ __launch_bounds__(256) void gemm_qkv(
    const float* __restrict__ xq, const float* __restrict__ xk, const float* __restrict__ xv,
    const float* __restrict__ wq, const float* __restrict__ wk, const float* __restrict__ wv,
    const float* __restrict__ bq, const float* __restrict__ bk, const float* __restrict__ bv,
    bf16_t* __restrict__ oq, bf16_t* __restrict__ ok, bf16_t* __restrict__ ov)
{
    __shared__ __align__(16) bf16_t lds_a[128][40];  // pad 32->40: conflict-free b128 reads
    __shared__ __align__(16) bf16_t lds_b[128][40];

    int z = blockIdx.z;
    const float* X    = (z == 0) ? xq : (z == 1) ? xk : xv;
    const float* W    = (z == 0) ? wq : (z == 1) ? wk : wv;
    const float* bias = (z == 0) ? bq : (z == 1) ? bk : bv;
    bf16_t*      out  = (z == 0) ? oq : (z == 1) ? ok : ov;

    int tid = threadIdx.x;
    int w = tid >> 6, l = tid & 63, lr = l & 15, lg = l >> 4;
    int m0 = blockIdx.x * 128, n0 = blockIdx.y * 128;
    int wm = (w >> 1) * 64, wn = (w & 1) * 64;
    int sr = tid >> 1, sc = (tid & 1) * 16;   // staging: row, 16-col chunk

    f32x4 zero4 = {0.f, 0.f, 0.f, 0.f};
    f32x4 acc[4][4];
    #pragma unroll
    for (int i = 0; i < 4; i++)
        #pragma unroll
        for (int j = 0; j < 4; j++) acc[i][j] = zero4;

    const float* asrc = X + (size_t)(m0 + sr) * D_ + sc;
    const float* bsrc = W + (size_t)(n0 + sr) * D_ + sc;

    for (int kt = 0; kt < D_ / 32; ++kt) {
        __syncthreads();
        #pragma unroll
        for (int i = 0; i < 4; i++) {
            f32x4 va = *(const f32x4*)(asrc + kt * 32 + i * 4);
            f32x4 vb = *(const f32x4*)(bsrc + kt * 32 + i * 4);
            bf16x4 ba, bb;
            #pragma unroll
            for (int j = 0; j < 4; j++) { ba[j] = (bf16_t)va[j]; bb[j] = (bf16_t)vb[j]; }
            *(bf16x4*)&lds_a[sr][sc + i * 4] = ba;
            *(bf16x4*)&lds_b[sr][sc + i * 4] = bb;
        }
        __syncthreads();
        bf16x8 af[4], bfr[4];
        #pragma unroll
        for (int i = 0; i < 4; i++) af[i]  = *(const bf16x8*)&lds_a[wm + i * 16 + lr][lg * 8];
        #pragma unroll
        for (int i = 0; i < 4; i++) bfr[i] = *(const bf16x8*)&lds_b[wn + i * 16 + lr][lg * 8];
        #pragma unroll
        for (int mi = 0; mi < 4; mi++)
            #pragma unroll
            for (int ni = 0; ni < 4; ni++)
                acc[mi][ni] = __builtin_amdgcn_mfma_f32_16x16x32_bf16(af[mi], bfr[ni], acc[mi][ni], 0, 0, 0);
    }

    // epilogue: +bias, cast bf16, scatter to [b][h][s][64]
    #pragma unroll
    for (int mi = 0; mi < 4; mi++) {
        int row = m0 + wm + mi * 16 + lg * 4;
        #pragma unroll
        for (int ni = 0; ni < 4; ni++) {
            int col = n0 + wn + ni * 16 + lr;
            float bval = bias[col];
            // row = b*2048 + s ; col = h*64 + d
            size_t obase = (((size_t)(row >> 11) * H_ + (col >> 6)) * SQ_) * HD_ + (size_t)(col & 63);
            #pragma unroll
            for (int r = 0; r < 4; r++) {
                int rr = row + r;
                out[obase + (size_t)(rr & 2047) * HD_] = (bf16_t)(acc[mi][ni][r] + bval);
            }
        }
    }
}

// ---------------------------------------------------------------------------
// Flash attention: per workgroup (b, h, qtile of 64). 4 waves x 16 q-rows.
// K loaded direct from global; V transposed through LDS; P via per-wave LDS.
__global__ __launch_bounds__(256) void attn_kernel(
    const bf16_t* __restrict__ qg, const bf16_t* __restrict__ kg,
    const bf16_t* __restrict__ vg, const float* __restrict__ bias,
    const int* __restrict__ mask, bf16_t* __restrict__ ctx)
{
    __shared__ __align__(16) bf16_t lds_vt[64][72];     // V^T tile [d][kpos]
    __shared__ __align__(16) bf16_t lds_p[4][16][72];   // per-wave P [qrow][kpos]

    int idx = blockIdx.x;          // ((h*32 + qt)*4 + b): batches adjacent for bias L3 reuse
    int b  = idx & 3;
    int qt = (idx >> 2) & 31;
    int h  = idx >> 7;
    int tid = threadIdx.x;
    int w  = tid >> 6;
    int l  = tid & 63;
    int lr = l & 15;
    int lg = l >> 4;

    const bf16_t* qptr = qg + (((size_t)b * H_ + h) * SQ_ + qt * 64 + w * 16 + lr) * HD_;
    bf16x8 qf0 = *(const bf16x8*)(qptr + lg * 8);
    bf16x8 qf1 = *(const bf16x8*)(qptr + 32 + lg * 8);

    const bf16_t* kbase = kg + ((size_t)b * H_ + h) * SK_ * HD_;
    const bf16_t* vbase = vg + ((size_t)b * H_ + h) * SK_ * HD_;
    const float* bias_base = bias + ((size_t)h * SQ_ + qt * 64 + w * 16 + lg * 4) * SK_;
    const int* mask_base = mask + (size_t)b * SK_;

    f32x4 zero4 = {0.f, 0.f, 0.f, 0.f};
    f32x4 ctx_acc[4];
    #pragma unroll
    for (int i = 0; i < 4; i++) ctx_acc[i] = zero4;
    float m_r[4], l_r[4];
    #pragma unroll
    for (int r = 0; r < 4; r++) { m_r[r] = -3.0e38f; l_r[r] = 0.f; }

    int vkp = tid >> 2;             // V staging: kpos row
    int vc  = (tid & 3) * 16;       // d chunk

    for (int kt = 0; kt < SK_ / 64; ++kt) {
        // ---- QK^T (K direct from global, 16B/lane coalesced) ----
        f32x4 sacc[4];
        #pragma unroll
        for (int i = 0; i < 4; i++) sacc[i] = zero4;
        #pragma unroll
        for (int ni = 0; ni < 4; ni++) {
            const bf16_t* kp = kbase + (size_t)(kt * 64 + ni * 16 + lr) * HD_;
            bf16x8 kf0 = *(const bf16x8*)(kp + lg * 8);
            bf16x8 kf1 = *(const bf16x8*)(kp + 32 + lg * 8);
            sacc[ni] = __builtin_amdgcn_mfma_f32_16x16x32_bf16(qf0, kf0, sacc[ni], 0, 0, 0);
            sacc[ni] = __builtin_amdgcn_mfma_f32_16x16x32_bf16(qf1, kf1, sacc[ni], 0, 0, 0);
        }

        __syncthreads();   // previous iteration's PV reads of lds_vt complete
        // ---- stage V^T ----
        {
            const bf16_t* vp = vbase + (size_t)(kt * 64 + vkp) * HD_ + vc;
            bf16x8 v0 = *(const bf16x8*)vp;
            bf16x8 v1 = *(const bf16x8*)(vp + 8);
            #pragma unroll
            for (int i = 0; i < 8; i++) lds_vt[vc + i][vkp] = v0[i];
            #pragma unroll
            for (int i = 0; i < 8; i++) lds_vt[vc + 8 + i][vkp] = v1[i];
        }

        // ---- online softmax (lane holds S[qrow=lg*4+r][kcol=ni*16+lr]) ----
        float maskf[4];
        #pragma unroll
        for (int ni = 0; ni < 4; ni++)
            maskf[ni] = mask_base[kt * 64 + ni * 16 + lr] ? 1.0f : 0.0f;

        float p[4][4];
        #pragma unroll
        for (int r = 0; r < 4; r++) {
            float mx = -3.0e38f;
            #pragma unroll
            for (int ni = 0; ni < 4; ni++) {
                float s = sacc[ni][r] * 0.125f +
                          bias_base[(size_t)r * SK_ + kt * 64 + ni * 16 + lr];
                s = (maskf[ni] != 0.f) ? s : -3.0e38f;
                p[ni][r] = s;
                mx = fmaxf(mx, s);
            }
            mx = fmaxf(mx, __shfl_xor(mx, 1));
            mx = fmaxf(mx, __shfl_xor(mx, 2));
            mx = fmaxf(mx, __shfl_xor(mx, 4));
            mx = fmaxf(mx, __shfl_xor(mx, 8));
            float nm = fmaxf(m_r[r], mx);
            float scale = __expf(m_r[r] - nm);
            float rs = 0.f;
            #pragma unroll
            for (int ni = 0; ni < 4; ni++) {
                float e = __expf(p[ni][r] - nm) * maskf[ni];  // masked -> exactly 0
                p[ni][r] = e;
                rs += e;
            }
            rs += __shfl_xor(rs, 1);
            rs += __shfl_xor(rs, 2);
            rs += __shfl_xor(rs, 4);
            rs += __shfl_xor(rs, 8);
            l_r[r] = l_r[r] * scale + rs;
            m_r[r] = nm;
            #pragma unroll
            for (int ni = 0; ni < 4; ni++) ctx_acc[ni][r] *= scale;
        }

        // ---- P -> LDS (D-layout scatter write, A-layout b128 read) ----
        #pragma unroll
        for (int ni = 0; ni < 4; ni++)
            #pragma unroll
            for (int r = 0; r < 4; r++)
                lds_p[w][lg * 4 + r][ni * 16 + lr] = (bf16_t)p[ni][r];

        __syncthreads();   // V^T staged, P visible

        // ---- PV ----
        bf16x8 pf0 = *(const bf16x8*)&lds_p[w][lr][lg * 8];
        bf16x8 pf1 = *(const bf16x8*)&lds_p[w][lr][32 + lg * 8];
        #pragma unroll
        for (int ni = 0; ni < 4; ni++) {
            bf16x8 vf0 = *(const bf16x8*)&lds_vt[ni * 16 + lr][lg * 8];
            bf16x8 vf1 = *(const bf16x8*)&lds_vt[ni * 16 + lr][32 + lg * 8];
            ctx_acc[ni] = __builtin_amdgcn_mfma_f32_16x16x32_bf16(pf0, vf0, ctx_acc[ni], 0, 0, 0);
            ctx_acc[ni] = __builtin_amdgcn_mfma_f32_16x16x32_bf16(pf1, vf1, ctx_acc[ni], 0, 0, 0);
        }
    }

    // ---- epilogue: ctx /= l, write [b][s][h*64+d] bf16 ----
    int qrow = qt * 64 + w * 16 + lg * 4;
    bf16_t* cb = ctx + (size_t)b * SQ_ * D_ + (size_t)h * HD_;
    #pragma unroll
    for (int r = 0; r < 4; r++) {
        float inv = (l_r[r] > 0.f) ? 1.0f / l_r[r] : 0.f;
        #pragma unroll
        for (int ni = 0; ni < 4; ni++)
            cb[(size_t)(qrow + r) * D_ + ni * 16 + lr] = (bf16_t)(ctx_acc[ni][r] * inv);
    }
}

// ---------------------------------------------------------------------------
// O projection: tmp = ctx(bf16) @ Wo^T + bo + query (residual), fp32 out
__global__ __launch_bounds__(256) void gemm_out(
    const bf16_t* __restrict__ A, const float* __restrict__ W,
    const float* __restrict__ bias, const float* __restrict__ resid,
    float* __restrict__ out)
{
    __shared__ __align__(16) bf16_t lds_a[128][40];
    __shared__ __align__(16) bf16_t lds_b[128][40];

    int tid = threadIdx.x;
    int w = tid >> 6, l = tid & 63, lr = l & 15, lg = l >> 4;
    int m0 = blockIdx.x * 128, n0 = blockIdx.y * 128;
    int wm = (w >> 1) * 64, wn = (w & 1) * 64;
    int sr = tid >> 1, sc = (tid & 1) * 16;

    f32x4 zero4 = {0.f, 0.f, 0.f, 0.f};
    f32x4 acc[4][4];
    #pragma unroll
    for (int i = 0; i < 4; i++)
        #pragma unroll
        for (int j = 0; j < 4; j++) acc[i][j] = zero4;

    const bf16_t* asrc = A + (size_t)(m0 + sr) * D_ + sc;
    const float*  bsrc = W + (size_t)(n0 + sr) * D_ + sc;

    for (int kt = 0; kt < D_ / 32; ++kt) {
        __syncthreads();
        {
            bf16x8 a0 = *(const bf16x8*)(asrc + kt * 32);
            bf16x8 a1 = *(const bf16x8*)(asrc + kt * 32 + 8);
            *(bf16x8*)&lds_a[sr][sc]     = a0;
            *(bf16x8*)&lds_a[sr][sc + 8] = a1;
            #pragma unroll
            for (int i = 0; i < 4; i++) {
                f32x4 vb = *(const f32x4*)(bsrc + kt * 32 + i * 4);
                bf16x4 bb;
                #pragma unroll
                for (int j = 0; j < 4; j++) bb[j] = (bf16_t)vb[j];
                *(bf16x4*)&lds_b[sr][sc + i * 4] = bb;
            }
        }
        __syncthreads();
        bf16x8 af[4], bfr[4];
        #pragma unroll
        for (int i = 0; i < 4; i++) af[i]  = *(const bf16x8*)&lds_a[wm + i * 16 + lr][lg * 8];
        #pragma unroll
        for (int i = 0; i < 4; i++) bfr[i] = *(const bf16x8*)&lds_b[wn + i * 16 + lr][lg * 8];
        #pragma unroll
        for (int mi = 0; mi < 4; mi++)
            #pragma unroll
            for (int ni = 0; ni < 4; ni++)
                acc[mi][ni] = __builtin_amdgcn_mfma_f32_16x16x32_bf16(af[mi], bfr[ni], acc[mi][ni], 0, 0, 0);
    }

    #pragma unroll
    for (int mi = 0; mi < 4; mi++) {
        int row = m0 + wm + mi * 16 + lg * 4;
        #pragma unroll
        for (int ni = 0; ni < 4; ni++) {
            int col = n0 + wn + ni * 16 + lr;
            float bval = bias[col];
            #pragma unroll
            for (int r = 0; r < 4; r++) {
                size_t o = (size_t)(row + r) * D_ + col;
                out[o] = acc[mi][ni][r] + bval + resid[o];
            }
        }
    }
}

// ---------------------------------------------------------------------------
// LayerNorm over D=1024, one block (256 threads) per row, fp32 in/out
__global__ __launch_bounds__(256) void ln_kernel(
    const float* __restrict__ x, const float* __restrict__ gamma,
    const float* __restrict__ beta, float* __restrict__ out)
{
    int row = blockIdx.x;
    int t = threadIdx.x;
    const float* src = x + (size_t)row * D_;
    f32x4 v = *(const f32x4*)(src + t * 4);
    float s  = v[0] + v[1] + v[2] + v[3];
    float s2 = v[0] * v[0] + v[1] * v[1] + v[2] * v[2] + v[3] * v[3];
    #pragma unroll
    for (int off = 32; off > 0; off >>= 1) {
        s  += __shfl_down(s, off);
        s2 += __shfl_down(s2, off);
    }
    __shared__ float red[8];
    int w = t >> 6, l = t & 63;
    if (l == 0) { red[w] = s; red[4 + w] = s2; }
    __syncthreads();
    if (t == 0) {
        red[0] = red[0] + red[1] + red[2] + red[3];
        red[4] = red[4] + red[5] + red[6] + red[7];
    }
    __syncthreads();
    float mu  = red[0] * (1.0f / D_);
    float var = red[4] * (1.0f / D_) - mu * mu;
    float rstd = rsqrtf(var + 1e-5f);
    f32x4 g  = *(const f32x4*)(gamma + t * 4);
    f32x4 be = *(const f32x4*)(beta + t * 4);
    f32x4 o;
    #pragma unroll
    for (int i = 0; i < 4; i++) o[i] = (v[i] - mu) * rstd * g[i] + be[i];
    *(f32x4*)(out + (size_t)row * D_ + t * 4) = o;
}

// ---------------------------------------------------------------------------
extern "C" void kernel_launch(void* const* d_in, const int* in_sizes, int n_in,
                              void* d_out, int out_size, void* d_ws, size_t ws_size,
                              hipStream_t stream)
{
    const float* query = (const float*)d_in[0];
    const float* key   = (const float*)d_in[1];
    const float* value = (const float*)d_in[2];
    const int*   mask  = (const int*)d_in[3];
    const float* bias  = (const float*)d_in[4];
    const float* Wq    = (const float*)d_in[5];
    const float* bq    = (const float*)d_in[6];
    const float* Wk    = (const float*)d_in[7];
    const float* bk    = (const float*)d_in[8];
    const float* Wv    = (const float*)d_in[9];
    const float* bv    = (const float*)d_in[10];
    const float* Wo    = (const float*)d_in[11];
    const float* bo    = (const float*)d_in[12];
    const float* gamma = (const float*)d_in[13];
    const float* beta  = (const float*)d_in[14];
    float* out = (float*)d_out;

    char* ws = (char*)d_ws;
    const size_t MB = 1024 * 1024;
    bf16_t* qb  = (bf16_t*)(ws);                 // 16 MB [B,H,SQ,64]
    bf16_t* kb  = (bf16_t*)(ws + 16 * MB);       // 16 MB
    bf16_t* vb  = (bf16_t*)(ws + 32 * MB);       // 16 MB
    bf16_t* ctx = (bf16_t*)(ws + 48 * MB);       // 16 MB [B,SQ,D]
    float*  tmp = (float*)(ws);                  // 32 MB, overlaps dead qb/kb

    gemm_qkv<<<dim3(64, 8, 3), 256, 0, stream>>>(query, key, value,
                                                 Wq, Wk, Wv, bq, bk, bv,
                                                 qb, kb, vb);
    attn_kernel<<<dim3(2048), 256, 0, stream>>>(qb, kb, vb, bias, mask, ctx);
    gemm_out<<<dim3(64, 8), 256, 0, stream>>>(ctx, Wo, bo, query, tmp);
    ln_kernel<<<dim3(8192), 256, 0, stream>>>(tmp, gamma, beta, out);
}